// Round 1
// baseline (750.328 us; speedup 1.0000x reference)
//
#include <hip/hip_runtime.h>

// MinHashSketch: sketch[512,128] = segment_min(x[500000,256] @ H[128,256]^T), empty -> 0
// R3: barrier-free main loop. Each wave owns 32 rows x 128 cols; MFMA A-fragments are
//     loaded global->reg directly (8 contiguous fp32 per lane, coalesced), split to
//     bf16 hi/lo in-register; B-fragments read directly from the pre-split
//     fragment-linear b1f/b2f (128 KB, L1/L2-resident). No LDS, no __syncthreads in
//     the k-loop (R2 had 16 barriers/block draining vmcnt(0) each). Numerics identical
//     to R2 (4-product split-bf16). Epilogue = R2's wave segmented suffix-min, remapped.

#define M_NODES 500000
#define KDIM    256
#define NHASH   128
#define NSEG    512

#define BM     128
#define BK     32
#define NCHUNK (KDIM / BK)   // 8

typedef __attribute__((ext_vector_type(8))) short bf16x8;
typedef __attribute__((ext_vector_type(4))) float f32x4;

__device__ __forceinline__ unsigned short f2bf(float f) {
    unsigned int u = __float_as_uint(f);
    u += 0x7FFFu + ((u >> 16) & 1u);           // round-to-nearest-even
    return (unsigned short)(u >> 16);
}
__device__ __forceinline__ float bf2f(unsigned short s) {
    return __uint_as_float(((unsigned int)s) << 16);
}
// Order-preserving float->uint encoding: uint-min == float-min
__device__ __forceinline__ unsigned int enc_f(float f) {
    unsigned int b = __float_as_uint(f);
    return (b & 0x80000000u) ? ~b : (b | 0x80000000u);
}

// split 8 fp32 -> bf16 hi + bf16 lo (residual), fragment order
__device__ __forceinline__ void split8(const float4& A, const float4& B,
                                       bf16x8& hi, bf16x8& lo) {
    const unsigned short h0 = f2bf(A.x), h1 = f2bf(A.y), h2 = f2bf(A.z), h3 = f2bf(A.w);
    const unsigned short h4 = f2bf(B.x), h5 = f2bf(B.y), h6 = f2bf(B.z), h7 = f2bf(B.w);
    hi = (bf16x8){(short)h0, (short)h1, (short)h2, (short)h3,
                  (short)h4, (short)h5, (short)h6, (short)h7};
    lo = (bf16x8){(short)f2bf(A.x - bf2f(h0)), (short)f2bf(A.y - bf2f(h1)),
                  (short)f2bf(A.z - bf2f(h2)), (short)f2bf(A.w - bf2f(h3)),
                  (short)f2bf(B.x - bf2f(h4)), (short)f2bf(B.y - bf2f(h5)),
                  (short)f2bf(B.z - bf2f(h6)), (short)f2bf(B.w - bf2f(h7))};
}

// Pre-split H into hi/lo bf16 in MFMA-B-fragment-linear order:
// value B[k][n] = H[n][k]; idx = ((k>>5)*8 + (n>>4))*512 + (((k>>3)&3)*16 + (n&15))*8 + (k&7)
__global__ void hsplit(const float* __restrict__ H,
                       unsigned short* __restrict__ b1f,
                       unsigned short* __restrict__ b2f) {
    const int t = blockIdx.x * 256 + threadIdx.x;   // 32768 elements
    const int n = t >> 8;        // hash row
    const int k = t & 255;
    const float h = H[t];
    const unsigned short s1 = f2bf(h);
    const unsigned short s2 = f2bf(h - bf2f(s1));
    const int idx = ((k >> 5) * 8 + (n >> 4)) * 512 + (((k >> 3) & 3) * 16 + (n & 15)) * 8 + (k & 7);
    b1f[idx] = s1;
    b2f[idx] = s2;
}

__global__ __launch_bounds__(256, 3)
void minhash_main(const float* __restrict__ x,
                  const unsigned int* __restrict__ batch_raw,
                  const unsigned short* __restrict__ b1f,
                  const unsigned short* __restrict__ b2f,
                  unsigned int* __restrict__ ws) {
    __shared__ __align__(16) float sc[8448];        // 64 cols x stride 132, epilogue only

    const int tid  = threadIdx.x;
    const int lane = tid & 63;
    const int w    = __builtin_amdgcn_readfirstlane(tid >> 6);  // wave 0..3
    const int quad = lane >> 4;
    const int c16  = lane & 15;
    const long long blockBase = (long long)blockIdx.x * BM;

    // wave w owns rows [w*32, w*32+32), all 128 cols
    const long long r0 = blockBase + w * 32 + c16;   // rt=0 fragment row
    const long long r1 = r0 + 16;                    // rt=1 fragment row
    const bool g0 = r0 < (long long)M_NODES;
    const bool g1 = r1 < (long long)M_NODES;
    const float* pa0 = x + r0 * KDIM + quad * 8;
    const float* pa1 = x + r1 * KDIM + quad * 8;

    f32x4 acc[2][8];
    #pragma unroll
    for (int rt = 0; rt < 2; ++rt)
        #pragma unroll
        for (int nt = 0; nt < 8; ++nt)
            acc[rt][nt] = (f32x4){0.f, 0.f, 0.f, 0.f};

    const float4 z4 = make_float4(0.f, 0.f, 0.f, 0.f);
    // software-pipelined A prefetch (1 chunk deep)
    float4 n0a = g0 ? *(const float4*)(pa0)     : z4;
    float4 n0b = g0 ? *(const float4*)(pa0 + 4) : z4;
    float4 n1a = g1 ? *(const float4*)(pa1)     : z4;
    float4 n1b = g1 ? *(const float4*)(pa1 + 4) : z4;

    const unsigned short* gb1 = b1f + lane * 8;
    const unsigned short* gb2 = b2f + lane * 8;

    for (int chunk = 0; chunk < NCHUNK; ++chunk) {
        const float4 c0a = n0a, c0b = n0b, c1a = n1a, c1b = n1b;
        if (chunk < NCHUNK - 1) {
            const int o = (chunk + 1) * BK;
            n0a = g0 ? *(const float4*)(pa0 + o)     : z4;
            n0b = g0 ? *(const float4*)(pa0 + o + 4) : z4;
            n1a = g1 ? *(const float4*)(pa1 + o)     : z4;
            n1b = g1 ? *(const float4*)(pa1 + o + 4) : z4;
        }
        bf16x8 a1_0, a2_0, a1_1, a2_1;
        split8(c0a, c0b, a1_0, a2_0);
        split8(c1a, c1b, a1_1, a2_1);

        const unsigned short* cb1 = gb1 + chunk * 4096;
        const unsigned short* cb2 = gb2 + chunk * 4096;
        #pragma unroll
        for (int nt = 0; nt < 8; ++nt) {
            const bf16x8 b1v = *(const bf16x8*)(cb1 + nt * 512);
            const bf16x8 b2v = *(const bf16x8*)(cb2 + nt * 512);
            acc[0][nt] = __builtin_amdgcn_mfma_f32_16x16x32_bf16(a1_0, b1v, acc[0][nt], 0, 0, 0);
            acc[0][nt] = __builtin_amdgcn_mfma_f32_16x16x32_bf16(a2_0, b1v, acc[0][nt], 0, 0, 0);
            acc[0][nt] = __builtin_amdgcn_mfma_f32_16x16x32_bf16(a1_0, b2v, acc[0][nt], 0, 0, 0);
            acc[0][nt] = __builtin_amdgcn_mfma_f32_16x16x32_bf16(a2_0, b2v, acc[0][nt], 0, 0, 0);
            acc[1][nt] = __builtin_amdgcn_mfma_f32_16x16x32_bf16(a1_1, b1v, acc[1][nt], 0, 0, 0);
            acc[1][nt] = __builtin_amdgcn_mfma_f32_16x16x32_bf16(a2_1, b1v, acc[1][nt], 0, 0, 0);
            acc[1][nt] = __builtin_amdgcn_mfma_f32_16x16x32_bf16(a1_1, b2v, acc[1][nt], 0, 0, 0);
            acc[1][nt] = __builtin_amdgcn_mfma_f32_16x16x32_bf16(a2_1, b2v, acc[1][nt], 0, 0, 0);
        }
    }

    // ---- epilogue: segment ids for this lane's node pair (reduction mapping) ----
    // batch dtype sniff: int64 -> word[499999] is high half of elem 249999 (==0);
    // int32 -> word[499999] == batch[499999] (sorted, ~511, nonzero).
    const bool is64 = (batch_raw[499999] == 0u);
    const long long* bb64 = (const long long*)batch_raw;
    const int*       bb32 = (const int*)batch_raw;

    const int p = lane;                // node-pair index: nodes 2p, 2p+1 (block-rel)
    const int cg = w;                  // col-group within the 64-col half
    const long long gn0 = blockBase + 2 * p;
    const long long gn1 = gn0 + 1;
    int seg0 = -1, seg1 = -1;
    if (gn0 < (long long)M_NODES) seg0 = is64 ? (int)bb64[gn0] : bb32[gn0];
    if (gn1 < (long long)M_NODES) seg1 = is64 ? (int)bb64[gn1] : bb32[gn1];

    #pragma unroll
    for (int h = 0; h < 2; ++h) {
        // every wave writes its 32 nodes for the 64 cols of this half
        // C layout: row = quad*4 + reg, col = c16  ->  node = w*32 + rt*16 + quad*4
        #pragma unroll
        for (int ct = 0; ct < 4; ++ct) {
            #pragma unroll
            for (int rt = 0; rt < 2; ++rt) {
                const int node = w * 32 + rt * 16 + quad * 4;
                const int colp = ct * 16 + c16;
                *(f32x4*)(sc + colp * 132 + node) = acc[rt][h * 4 + ct];
            }
        }
        __syncthreads();

        // pair-merge + wave segmented suffix-min over 64 node-pairs
        float v[16];
        int seg;
        if (seg0 == seg1) {
            seg = seg0;
            #pragma unroll
            for (int j = 0; j < 16; ++j) {
                const float2 nv = *(const float2*)(sc + (cg * 16 + j) * 132 + 2 * p);
                v[j] = fminf(nv.x, nv.y);
            }
        } else {
            seg = seg1;
            #pragma unroll
            for (int j = 0; j < 16; ++j) {
                const float2 nv = *(const float2*)(sc + (cg * 16 + j) * 132 + 2 * p);
                if (seg0 >= 0)
                    atomicMin(&ws[seg0 * NHASH + h * 64 + cg * 16 + j], enc_f(nv.x));
                v[j] = nv.y;
            }
        }
        #pragma unroll
        for (int d = 1; d < 64; d <<= 1) {
            const int  oseg = __shfl_down(seg, d, 64);
            const bool ok   = (lane + d < 64) && (oseg == seg);
            #pragma unroll
            for (int j = 0; j < 16; ++j) {
                const float ov = __shfl_down(v[j], d, 64);
                if (ok) v[j] = fminf(v[j], ov);
            }
        }
        const int pseg = __shfl_up(seg, 1, 64);
        if (seg >= 0 && (lane == 0 || pseg != seg)) {
            #pragma unroll
            for (int j = 0; j < 16; ++j)
                atomicMin(&ws[seg * NHASH + h * 64 + cg * 16 + j], enc_f(v[j]));
        }
        __syncthreads();
    }
}

__global__ void minhash_finalize(const unsigned int* __restrict__ ws,
                                 float* __restrict__ out) {
    const int i = blockIdx.x * blockDim.x + threadIdx.x;
    if (i < NSEG * NHASH) {
        const unsigned int u = ws[i];
        out[i] = (u == 0xFFFFFFFFu)
                     ? 0.0f   // untouched sentinel == empty segment
                     : ((u & 0x80000000u) ? __uint_as_float(u ^ 0x80000000u)
                                          : __uint_as_float(~u));
    }
}

extern "C" void kernel_launch(void* const* d_in, const int* in_sizes, int n_in,
                              void* d_out, int out_size, void* d_ws, size_t ws_size,
                              hipStream_t stream) {
    const float* x = (const float*)d_in[0];
    const unsigned int* batch = (const unsigned int*)d_in[1];
    const float* H = (const float*)d_in[3];

    unsigned int*   ws  = (unsigned int*)d_ws;
    unsigned short* b1f = (unsigned short*)((char*)d_ws + 256 * 1024);
    unsigned short* b2f = (unsigned short*)((char*)d_ws + 320 * 1024);

    hipMemsetAsync(d_ws, 0xFF, NSEG * NHASH * sizeof(unsigned int), stream);
    hsplit<<<(KDIM * NHASH) / 256, 256, 0, stream>>>(H, b1f, b2f);

    const int grid = (M_NODES + BM - 1) / BM;  // 3907
    minhash_main<<<grid, 256, 0, stream>>>(x, batch, b1f, b2f, ws);
    minhash_finalize<<<(NSEG * NHASH + 255) / 256, 256, 0, stream>>>(ws, (float*)d_out);
}